// Round 11
// baseline (669.813 us; speedup 1.0000x reference)
//
#include <hip/hip_runtime.h>
#include <hip/hip_bf16.h>
#include <hip/hip_fp16.h>

typedef __hip_bfloat16 bf16;
typedef unsigned short ushort_t;
typedef unsigned short us8 __attribute__((ext_vector_type(8)));
typedef _Float16 half8 __attribute__((ext_vector_type(8)));
typedef _Float16 half4v __attribute__((ext_vector_type(4)));
typedef float f32x4 __attribute__((ext_vector_type(4)));

#define NEG 0.2f
#define LNEPS 1e-5f
#define BWD 512                 // CSR bucket width (nodes)

__device__ __forceinline__ int plaus(unsigned int lo){
    lo &= 0x7FFFu;
    if (lo == 0) return 1;
    unsigned int ex = (lo >> 7) & 0xFF;
    return (ex >= 100 && ex <= 140) ? 1 : 0;
}

__device__ __forceinline__ float decode_slot(const ushort_t* s, long long i, int fl){
    long long base = i << fl;
    unsigned int hi = s[base + fl];
    unsigned int lo = s[base];
    unsigned int bits = (hi << 16) | (lo * (unsigned int)fl);
    return __uint_as_float(bits);
}

// order-preserving float<->uint encoding for atomicMax on floats (incl. negatives)
__device__ __forceinline__ unsigned encf(float f){
    int b = __float_as_int(f);
    return (b >= 0) ? ((unsigned)b | 0x80000000u) : (unsigned)(~b);
}
__device__ __forceinline__ float decf(unsigned k){
    return (k & 0x80000000u) ? __uint_as_float(k & 0x7FFFFFFFu)
                             : __uint_as_float(~k);
}

// ---------- init: param convert (inline detect) + flags + mxs + edge histogram ----------
#define P_TOTAL 56577
#define CONV_BLKS 222
__global__ __launch_bounds__(256) void k_init(const void* p0, const void* p1, const void* p2,
        const void* p3, const void* p4, const void* p5, const void* p6, const void* p7,
        const void* p8, const void* p9, const void* p10, const void* p11, const void* p12,
        const void* p13, const void* p14, const void* xs,
        const int* __restrict__ row, const int* __restrict__ col, int E, int NBK,
        int* flags, float* P, int* bcnt, unsigned* mxsu){
    __shared__ int lh[512];
    int t = threadIdx.x;
    if (blockIdx.x >= CONV_BLKS){
        int hb = blockIdx.x - CONV_BLKS;
        for (int i = t; i < 2*NBK; i += 256) lh[i] = 0;
        __syncthreads();
        for (long long e = (long long)hb*256 + t; e < E; e += (long long)256*256){
            atomicAdd(&lh[row[e] >> 9], 1);
            atomicAdd(&lh[NBK + (col[e] >> 9)], 1);
        }
        __syncthreads();
        for (int i = t; i < 2*NBK; i += 256){
            int v = lh[i];
            if (v) atomicAdd(&bcnt[i], v);
        }
        return;
    }
    if (blockIdx.x == 0){
        if (t < 9){
            const void* dt[9] = {xs, p0, p2, p3, p4, p5, p7, p11, p13};
            const ushort_t* w = (const ushort_t*)dt[t];
            int all_bf = 1;
            for (int i = 0; i < 16; i++) all_bf &= plaus((unsigned int)w[i]);
            flags[t] = all_bf ? 0 : 1;
        } else if (t == 9){
            const ushort_t* w = (const ushort_t*)p9;
            flags[9] = (w[0] == 0x3F80u) ? 0 : 1;
        }
        if (t < 32) mxsu[t] = 0u;            // encoded -inf for 3 layer slots
    }
    int idx = blockIdx.x*256 + t;
    if (idx >= P_TOTAL) return;
    const int sizes[15] = {4096,64,12288,12288,192,192,192,24576,192,192,192,2048,32,32,1};
    const int fidx[15]  = {1,  -1,  2,    3,    4,  5,  -1, 6,    -1, 9,  -1, 7,   -1,8, -1};
    const void* ptrs[15] = {p0,p1,p2,p3,p4,p5,p6,p7,p8,p9,p10,p11,p12,p13,p14};
    int s = 0, base = 0;
    while (idx - base >= sizes[s]){ base += sizes[s]; s++; }
    int li = idx - base;
    int fi = fidx[s];
    int fl = 0;
    if (fi == 9){
        const ushort_t* w = (const ushort_t*)ptrs[s];
        fl = (w[0] == 0x3F80u) ? 0 : 1;
    } else if (fi >= 0){
        const ushort_t* w = (const ushort_t*)ptrs[s];
        int all_bf = 1;
        for (int i = 0; i < 16; i++) all_bf &= plaus((unsigned int)w[i]);
        fl = all_bf ? 0 : 1;
    }
    P[idx] = decode_slot((const ushort_t*)ptrs[s], li, fl);
}

// ---------- scan + weight precompute, one launch (block-role split) ----------
// blocks 0,1: bucket exclusive scan. blocks 2..: Wt16 (e8-folded fused, [i][p][j]) /
// b2c / Bg (MFMA frags for G) / Wr16 (readout W1, [k][j]).
#define PRW_B0 (3*8192)
#define PRW_B1 (PRW_B0 + 192)
#define PRW_B2 (PRW_B1 + 3*5120)
#define PRW_B3 (PRW_B2 + 2048)
__global__ __launch_bounds__(256) void kb_scanprew(const int* __restrict__ bcnt,
        int* __restrict__ bptr_r, int* __restrict__ bptr_c,
        int* __restrict__ bcur_r, int* __restrict__ bcur_c, int NBK, int E,
        const float* __restrict__ fus_W, const float* __restrict__ e8_W,
        const float* __restrict__ gat_b, const float* __restrict__ fus_b,
        const float* __restrict__ gat_W, const float* __restrict__ att_src,
        const float* __restrict__ att_dst, const float* __restrict__ r_W1,
        _Float16* __restrict__ Wt16, float* __restrict__ b2c,
        _Float16* __restrict__ Bg, _Float16* __restrict__ Wr16){
    __shared__ int sh[256];
    int t = threadIdx.x;
    if (blockIdx.x < 2){
        int side = blockIdx.x;
        const int* c = bcnt + side*NBK;
        int* bp = side ? bptr_c : bptr_r;
        int* bc = side ? bcur_c : bcur_r;
        int v = (t < NBK) ? c[t] : 0;
        sh[t] = v; __syncthreads();
        for (int off = 1; off < 256; off <<= 1){
            int add = (t >= off) ? sh[t-off] : 0;
            __syncthreads();
            sh[t] += add;
            __syncthreads();
        }
        if (t < NBK){ int e = sh[t] - v; bp[t] = e; bc[t] = e; }
        if (t == 0) bp[NBK] = E;
        return;
    }
    int idx = (blockIdx.x - 2)*256 + t;
    if (idx < PRW_B0){
        // Wt16[i][p][j]: fused fusion weight for input p, output j (e8 folded for p<64)
        int i = idx / 8192; int rem = idx & 8191;
        int p = rem >> 6, j = rem & 63;
        float v;
        if (p < 64){
            const float* fw = fus_W + (size_t)i*8192 + (size_t)j*128;
            const float* ew = e8_W + (size_t)i*4096;
            float acc = 0.f;
            for (int q = 0; q < 64; q++) acc += fw[q] * ew[q*64 + p];
            v = acc;
        } else {
            v = fus_W[(size_t)i*8192 + (size_t)j*128 + p];
        }
        Wt16[idx] = (_Float16)v;
    } else if (idx < PRW_B1){
        int t2 = idx - PRW_B0;
        int i = t2 >> 6, j = t2 & 63;
        const float* fw = fus_W + (size_t)i*8192 + (size_t)j*128 + 64;
        float acc = fus_b[i*64+j];
        for (int p = 0; p < 64; p++) acc += gat_b[i*64+p] * fw[p];
        b2c[t2] = acc;
    } else if (idx < PRW_B2){
        int t3 = idx - PRW_B1;
        int i = t3 / 5120; int rem = t3 % 5120;
        int j = rem & 7, lane = (rem >> 3) & 63, kk = (rem >> 9) & 1, tt = rem >> 10;
        int k = kk*32 + (lane >> 4)*8 + j;
        int nn = lane & 15;
        float v;
        if (tt < 4){
            v = gat_W[(size_t)i*4096 + k*64 + (tt*16 + nn)];
        } else if (nn < 8){
            int hx = nn >> 1;
            const float* att = (nn & 1) ? att_dst : att_src;
            float acc = 0.f;
            for (int cc = 0; cc < 16; cc++)
                acc += gat_W[(size_t)i*4096 + k*64 + hx*16 + cc] * att[i*64 + hx*16 + cc];
            v = acc;
        } else {
            v = 0.f;
        }
        Bg[t3] = (_Float16)v;
    } else if (idx < PRW_B3){
        int t4 = idx - PRW_B2;
        int k = t4 >> 5, j = t4 & 31;
        Wr16[t4] = (_Float16)r_W1[j*64 + k];
    }
}

// both sides in one launch; stage packed to 4B: (in-bucket node)<<23 | payload
__global__ __launch_bounds__(1024) void kb_bin(const int* __restrict__ row,
        const int* __restrict__ col, int* __restrict__ bcur_r, int* __restrict__ bcur_c,
        unsigned* __restrict__ stage_r, unsigned* __restrict__ stage_c, int NBK, int E){
    __shared__ int lh[256], lbase[256];
    int side = blockIdx.x >> 8;
    int bid  = blockIdx.x & 255;
    const int* key = side ? col : row;
    const int* pay = side ? row : col;
    int* bcur = side ? bcur_c : bcur_r;
    unsigned* stage = side ? stage_c : stage_r;
    int t = threadIdx.x;
    for (long long tile = (long long)bid*1024; tile < E; tile += (long long)256*1024){
        for (int i = t; i < NBK; i += 1024) lh[i] = 0;
        __syncthreads();
        int e = (int)tile + t;
        int k = 0, p = 0, b = -1, rank = 0;
        if (e < E){
            k = key[e]; p = pay[e]; b = k >> 9;
            rank = atomicAdd(&lh[b], 1);
        }
        __syncthreads();
        for (int i = t; i < NBK; i += 1024){
            int c = lh[i];
            lbase[i] = c ? atomicAdd(&bcur[i], c) : 0;
        }
        __syncthreads();
        if (b >= 0) stage[lbase[b] + rank] = ((unsigned)(k & 511) << 23) | (unsigned)p;
        __syncthreads();
    }
}

// both sides in one launch: blocks 0..NBK-1 row, NBK..2NBK-1 col
__global__ __launch_bounds__(1024) void kb_place(const unsigned* __restrict__ stage_r,
        const unsigned* __restrict__ stage_c, const int* __restrict__ bptr_r,
        const int* __restrict__ bptr_c, int* __restrict__ ptr_r, int* __restrict__ ptr_c,
        int* __restrict__ re_col, int* __restrict__ ce_row,
        float* __restrict__ dinv, int NBK, int N, int E){
    __shared__ int lcnt[BWD], lsc[BWD], lcur[BWD];
    int side = blockIdx.x >= NBK;
    int b = blockIdx.x - (side ? NBK : 0);
    const unsigned* stage = side ? stage_c : stage_r;
    const int* bptr = side ? bptr_c : bptr_r;
    int* ptr = side ? ptr_c : ptr_r;
    int* outarr = side ? ce_row : re_col;
    int wantdinv = side;
    int s = bptr[b], e = bptr[b+1];
    int t = threadIdx.x;
    if (t < BWD) lcnt[t] = 0;
    __syncthreads();
    for (int i = s + t; i < e; i += 1024)
        atomicAdd(&lcnt[stage[i] >> 23], 1);
    __syncthreads();
    if (t < BWD) lsc[t] = lcnt[t];
    __syncthreads();
    for (int off = 1; off < BWD; off <<= 1){
        int add = (t >= off && t < BWD) ? lsc[t-off] : 0;
        __syncthreads();
        if (t < BWD) lsc[t] += add;
        __syncthreads();
    }
    if (t < BWD){
        int node = (b << 9) + t;
        int excl = lsc[t] - lcnt[t];
        lcur[t] = excl;
        if (node < N){
            ptr[node] = s + excl;
            if (wantdinv) dinv[node] = lcnt[t] > 0 ? rsqrtf((float)lcnt[t]) : 0.f;
        }
    }
    if (b == 0 && t == 0) ptr[N] = E;
    __syncthreads();
    for (int i = s + t; i < e; i += 1024){
        unsigned rec = stage[i];
        int pos = s + atomicAdd(&lcur[rec >> 23], 1);
        outarr[pos] = (int)(rec & 0x7FFFFFu);
    }
}

// ---------- embed + layer-0 G projection (vectorized x loads, tbuf transpose) ----------
__global__ __launch_bounds__(256) void k_embed_g(const ushort_t* __restrict__ xs,
        const int* __restrict__ flags, const float* __restrict__ W,
        const float* __restrict__ b, const float* __restrict__ dinv,
        const _Float16* __restrict__ Bgn,
        __half* __restrict__ h16, __half* __restrict__ ht16, __half* __restrict__ G16,
        float* __restrict__ a_s, float* __restrict__ a_d, float* __restrict__ mxs, int N){
    __shared__ float redm[4][8];
    __shared__ _Float16 tbuf[4][1024];
    int lane = threadIdx.x & 63;
    int wv = threadIdx.x >> 6;
    int q = lane >> 4, c = lane & 15;
    _Float16* tb = tbuf[wv];
    int fl = flags[0];
    half8 Be[4][2];
    #pragma unroll
    for (int t = 0; t < 4; t++){
        #pragma unroll
        for (int kk = 0; kk < 2; kk++){
            half8 v;
            #pragma unroll
            for (int j = 0; j < 8; j++)
                v[j] = (_Float16)W[(t*16 + c)*64 + kk*32 + q*8 + j];
            Be[t][kk] = v;
        }
    }
    half8 Bg[5][2];
    const half8* Bgp = (const half8*)Bgn;
    #pragma unroll
    for (int t = 0; t < 5; t++)
        #pragma unroll
        for (int kk = 0; kk < 2; kk++)
            Bg[t][kk] = Bgp[(t*2+kk)*64 + lane];
    float bj[4];
    #pragma unroll
    for (int t = 0; t < 4; t++) bj[t] = b[t*16 + c];
    float lmax = -1e30f;
    int tiles = (N + 15) >> 4;
    int wid = (blockIdx.x*blockDim.x + threadIdx.x) >> 6;
    int nw  = (gridDim.x*blockDim.x) >> 6;
    for (int tile = wid; tile < tiles; tile += nw){
        int nb = tile << 4;
        int anode = nb + c; if (anode >= N) anode = N - 1;
        half8 A0, A1;
        if (fl == 0){
            const us8* xv = (const us8*)xs;
            us8 r0 = xv[(size_t)anode*8 + q];
            us8 r1 = xv[(size_t)anode*8 + 4 + q];
            #pragma unroll
            for (int j = 0; j < 8; j++){
                A0[j] = (_Float16)__uint_as_float((unsigned)r0[j] << 16);
                A1[j] = (_Float16)__uint_as_float((unsigned)r1[j] << 16);
            }
        } else {
            const f32x4* xf = (const f32x4*)xs;
            f32x4 f0 = xf[(size_t)anode*16 + q*2];
            f32x4 f1 = xf[(size_t)anode*16 + q*2 + 1];
            f32x4 f2 = xf[(size_t)anode*16 + 8 + q*2];
            f32x4 f3 = xf[(size_t)anode*16 + 8 + q*2 + 1];
            #pragma unroll
            for (int j = 0; j < 4; j++){
                A0[j] = (_Float16)f0[j]; A0[4+j] = (_Float16)f1[j];
                A1[j] = (_Float16)f2[j]; A1[4+j] = (_Float16)f3[j];
            }
        }
        f32x4 acc[4];
        #pragma unroll
        for (int t = 0; t < 4; t++){
            f32x4 z = {0.f, 0.f, 0.f, 0.f};
            z = __builtin_amdgcn_mfma_f32_16x16x32_f16(A0, Be[t][0], z, 0, 0, 0);
            z = __builtin_amdgcn_mfma_f32_16x16x32_f16(A1, Be[t][1], z, 0, 0, 0);
            acc[t] = z;
        }
        #pragma unroll
        for (int r = 0; r < 4; r++){
            int node = nb + q*4 + r;
            int nd2 = q*4 + r;
            #pragma unroll
            for (int t = 0; t < 4; t++){
                float out = acc[t][r] + bj[t];
                int byte = nd2*128 + (t*16 + c)*2;
                byte ^= (nd2 & 7) << 4;
                *(_Float16*)((char*)tb + byte) = (_Float16)out;
                if (node < N){
                    h16[(size_t)node*64 + t*16 + c] = __float2half(out);
                    ht16[(size_t)node*64 + t*16 + c] = __float2half(dinv[node]*out);
                }
            }
        }
        int b0 = (c*128 + 16*q) ^ ((c & 7) << 4);
        int b1 = (c*128 + 64 + 16*q) ^ ((c & 7) << 4);
        half8 A0g = *(half8*)((char*)tb + b0);
        half8 A1g = *(half8*)((char*)tb + b1);
        f32x4 gacc[5];
        #pragma unroll
        for (int t = 0; t < 5; t++){
            f32x4 z = {0.f, 0.f, 0.f, 0.f};
            z = __builtin_amdgcn_mfma_f32_16x16x32_f16(A0g, Bg[t][0], z, 0, 0, 0);
            z = __builtin_amdgcn_mfma_f32_16x16x32_f16(A1g, Bg[t][1], z, 0, 0, 0);
            gacc[t] = z;
        }
        #pragma unroll
        for (int r = 0; r < 4; r++) lmax = fmaxf(lmax, gacc[4][r]);
        #pragma unroll
        for (int r = 0; r < 4; r++){
            int node = nb + q*4 + r;
            if (node < N){
                #pragma unroll
                for (int t = 0; t < 4; t++)
                    G16[(size_t)node*64 + t*16 + c] = __float2half(gacc[t][r]);
                if (c < 8){
                    int hx = c >> 1;
                    if (c & 1) a_d[node*4+hx] = gacc[4][r];
                    else       a_s[node*4+hx] = gacc[4][r];
                }
            }
        }
    }
    lmax = fmaxf(lmax, __shfl_xor(lmax, 16));
    lmax = fmaxf(lmax, __shfl_xor(lmax, 32));
    if (lane < 8) redm[wv][lane] = lmax;
    __syncthreads();
    if (threadIdx.x < 8){
        float m = fmaxf(fmaxf(redm[0][threadIdx.x], redm[1][threadIdx.x]),
                        fmaxf(redm[2][threadIdx.x], redm[3][threadIdx.x]));
        int hx = threadIdx.x >> 1;
        int ix = (threadIdx.x & 1) ? 4 + hx : hx;
        atomicMax((unsigned*)mxs + ix, encf(m));
    }
}

// ---------- G projection (layers 1,2): h16 @ gat_W via MFMA ----------
__global__ __launch_bounds__(256) void k_gat_g(const __half* __restrict__ h16,
        const _Float16* __restrict__ Bg, __half* __restrict__ G16,
        float* __restrict__ a_s, float* __restrict__ a_d, float* __restrict__ mxs, int N){
    __shared__ float redm[4][8];
    int lane = threadIdx.x & 63;
    int wv = threadIdx.x >> 6;
    int q = lane >> 4, c = lane & 15;
    half8 B[5][2];
    const half8* Bp = (const half8*)Bg;
    #pragma unroll
    for (int t = 0; t < 5; t++)
        #pragma unroll
        for (int kk = 0; kk < 2; kk++)
            B[t][kk] = Bp[(t*2+kk)*64 + lane];
    float lmax = -1e30f;
    int tiles = (N + 15) >> 4;
    int wid = (blockIdx.x*blockDim.x + threadIdx.x) >> 6;
    int nw  = (gridDim.x*blockDim.x) >> 6;
    for (int tile = wid; tile < tiles; tile += nw){
        int nb = tile << 4;
        int anode = nb + c; if (anode >= N) anode = N - 1;
        const half8* ap = (const half8*)(h16 + (size_t)anode*64);
        half8 A0 = ap[q];
        half8 A1 = ap[4 + q];
        f32x4 acc[5];
        #pragma unroll
        for (int t = 0; t < 5; t++){
            f32x4 z = {0.f, 0.f, 0.f, 0.f};
            z = __builtin_amdgcn_mfma_f32_16x16x32_f16(A0, B[t][0], z, 0, 0, 0);
            z = __builtin_amdgcn_mfma_f32_16x16x32_f16(A1, B[t][1], z, 0, 0, 0);
            acc[t] = z;
        }
        #pragma unroll
        for (int r = 0; r < 4; r++) lmax = fmaxf(lmax, acc[4][r]);
        #pragma unroll
        for (int r = 0; r < 4; r++){
            int node = nb + q*4 + r;
            if (node < N){
                #pragma unroll
                for (int t = 0; t < 4; t++)
                    G16[(size_t)node*64 + t*16 + c] = __float2half(acc[t][r]);
                if (c < 8){
                    int hx = c >> 1;
                    if (c & 1) a_d[node*4+hx] = acc[4][r];
                    else       a_s[node*4+hx] = acc[4][r];
                }
            }
        }
    }
    lmax = fmaxf(lmax, __shfl_xor(lmax, 16));
    lmax = fmaxf(lmax, __shfl_xor(lmax, 32));
    if (lane < 8) redm[wv][lane] = lmax;
    __syncthreads();
    if (threadIdx.x < 8){
        float m = fmaxf(fmaxf(redm[0][threadIdx.x], redm[1][threadIdx.x]),
                        fmaxf(redm[2][threadIdx.x], redm[3][threadIdx.x]));
        int hx = threadIdx.x >> 1;
        int ix = (threadIdx.x & 1) ? 4 + hx : hx;
        atomicMax((unsigned*)mxs + ix, encf(m));
    }
}

__device__ __forceinline__ float leaky(float t){ return t > 0.f ? t : NEG*t; }

// ---------- gather + VALU-fuse + LN (layers 0,1) ----------
// Gather phase identical to the proven k_gather (latency-bound, 3.65 TB/s, VALU 23%
// idle). Fusion matmul (128->64 per node, 1.64 GFLOP/layer ~ 3us GPU-wide) runs on
// the idle VALU with weights in LDS; per-node inputs pass wave-locally through LDS
// (same-wave DS ordering, the verified tbuf pattern). Aj/xg never touch global.
// h/ht are ping-pong buffers: reads neighbors' layer-i values, writes layer-i+1.
__global__ __launch_bounds__(256) void k_gfuse(
        const __half* __restrict__ ht_src, const __half* __restrict__ h_src,
        const __half* __restrict__ G16,
        const float* __restrict__ a_s, const float* __restrict__ a_d,
        const float* __restrict__ mxs, const float* __restrict__ dinv,
        const int* __restrict__ row_ptr, const int* __restrict__ re_col,
        const int* __restrict__ col_ptr, const int* __restrict__ ce_row,
        const _Float16* __restrict__ Wt16, const float* __restrict__ b2c,
        const float* __restrict__ ln_g, const float* __restrict__ ln_b,
        __half* __restrict__ h_dst, __half* __restrict__ ht_dst, int N){
    __shared__ _Float16 Wl[8192];        // 16 KB fused weights [p][j]
    __shared__ _Float16 inb[4][8][128];  // 8 KB per-wave node inputs
    {
        const half8* src = (const half8*)Wt16;
        half8* dst = (half8*)Wl;
        for (int i = threadIdx.x; i < 1024; i += 256) dst[i] = src[i];
    }
    __syncthreads();
    int lane = threadIdx.x & 63;
    int wv = threadIdx.x >> 6;
    int grp = lane >> 3, sub = lane & 7, hh = sub >> 1;
    int wid = (blockIdx.x*blockDim.x + threadIdx.x) >> 6;
    int v = wid*8 + grp;
    if (v >= N) return;
    const us8* htb = (const us8*)ht_src;
    const us8* gb  = (const us8*)G16;
    const unsigned* mup = (const unsigned*)mxs;
    float sh = leaky(decf(mup[hh]) + decf(mup[4+hh]));
    // ---- gather phase R ----
    int rs = row_ptr[v], re = row_ptr[v+1];
    float a0[8] = {0,0,0,0,0,0,0,0}, a1[8] = {0,0,0,0,0,0,0,0};
    float a2[8] = {0,0,0,0,0,0,0,0}, a3[8] = {0,0,0,0,0,0,0,0};
    int i = rs;
    for (; i + 3 < re; i += 4){
        us8 q0 = htb[(size_t)re_col[i]*8 + sub];
        us8 q1 = htb[(size_t)re_col[i+1]*8 + sub];
        us8 q2 = htb[(size_t)re_col[i+2]*8 + sub];
        us8 q3 = htb[(size_t)re_col[i+3]*8 + sub];
        #pragma unroll
        for (int j = 0; j < 8; j++){
            a0[j] += __half2float(__ushort_as_half(q0[j]));
            a1[j] += __half2float(__ushort_as_half(q1[j]));
            a2[j] += __half2float(__ushort_as_half(q2[j]));
            a3[j] += __half2float(__ushort_as_half(q3[j]));
        }
    }
    for (; i < re; i++){
        us8 q0 = htb[(size_t)re_col[i]*8 + sub];
        #pragma unroll
        for (int j = 0; j < 8; j++) a0[j] += __half2float(__ushort_as_half(q0[j]));
    }
    float dv = dinv[v];
    float ajv[8];
    #pragma unroll
    for (int j = 0; j < 8; j++) ajv[j] = dv*((a0[j]+a1[j]) + (a2[j]+a3[j]));
    // ---- gather phase C ----
    float adv = a_d[v*4+hh];
    float eesl = __expf(leaky(a_s[v*4+hh] + adv) - sh);
    float s0 = eesl, s1 = 0.f, s2 = 0.f, s3 = 0.f;
    {
        us8 g0 = gb[(size_t)v*8 + sub];
        #pragma unroll
        for (int j = 0; j < 8; j++){
            a0[j] = eesl * __half2float(__ushort_as_half(g0[j]));
            a1[j] = 0.f; a2[j] = 0.f; a3[j] = 0.f;
        }
    }
    int cs = col_ptr[v], ce = col_ptr[v+1];
    i = cs;
    for (; i + 3 < ce; i += 4){
        int r0 = ce_row[i], r1 = ce_row[i+1], r2 = ce_row[i+2], r3 = ce_row[i+3];
        float e0 = __expf(leaky(a_s[r0*4+hh] + adv) - sh);
        float e1 = __expf(leaky(a_s[r1*4+hh] + adv) - sh);
        float e2 = __expf(leaky(a_s[r2*4+hh] + adv) - sh);
        float e3 = __expf(leaky(a_s[r3*4+hh] + adv) - sh);
        us8 q0 = gb[(size_t)r0*8 + sub];
        us8 q1 = gb[(size_t)r1*8 + sub];
        us8 q2 = gb[(size_t)r2*8 + sub];
        us8 q3 = gb[(size_t)r3*8 + sub];
        #pragma unroll
        for (int j = 0; j < 8; j++){
            a0[j] += e0 * __half2float(__ushort_as_half(q0[j]));
            a1[j] += e1 * __half2float(__ushort_as_half(q1[j]));
            a2[j] += e2 * __half2float(__ushort_as_half(q2[j]));
            a3[j] += e3 * __half2float(__ushort_as_half(q3[j]));
        }
        s0 += e0; s1 += e1; s2 += e2; s3 += e3;
    }
    for (; i < ce; i++){
        int r0 = ce_row[i];
        float e0 = __expf(leaky(a_s[r0*4+hh] + adv) - sh);
        us8 q0 = gb[(size_t)r0*8 + sub];
        #pragma unroll
        for (int j = 0; j < 8; j++) a0[j] += e0 * __half2float(__ushort_as_half(q0[j]));
        s0 += e0;
    }
    float inv = 1.f/((s0+s1)+(s2+s3));
    // ---- fuse: inputs to LDS, VALU matmul, residual, LN ----
    _Float16* myin = inb[wv][grp];
    half8 ha, hx;
    #pragma unroll
    for (int j = 0; j < 8; j++){
        ha[j] = (_Float16)ajv[j];
        hx[j] = (_Float16)(((a0[j]+a1[j]) + (a2[j]+a3[j]))*inv);
    }
    *(half8*)(myin + sub*8)      = ha;
    *(half8*)(myin + 64 + sub*8) = hx;
    float y[8];
    us8 hr = ((const us8*)h_src)[(size_t)v*8 + sub];
    #pragma unroll
    for (int j = 0; j < 8; j++)
        y[j] = b2c[sub*8+j] + __half2float(__ushort_as_half(hr[j]));
    for (int pp = 0; pp < 16; pp++){
        half8 ib = *(half8*)(myin + pp*8);
        #pragma unroll
        for (int e = 0; e < 8; e++){
            float xin = (float)ib[e];
            half8 w = *(half8*)(Wl + (pp*8+e)*64 + sub*8);
            #pragma unroll
            for (int j = 0; j < 8; j++) y[j] += xin * (float)w[j];
        }
    }
    float s = ((y[0]+y[1])+(y[2]+y[3])) + ((y[4]+y[5])+(y[6]+y[7]));
    s += __shfl_xor(s, 1); s += __shfl_xor(s, 2); s += __shfl_xor(s, 4);
    float mu = s * (1.f/64.f);
    float var = 0.f;
    #pragma unroll
    for (int j = 0; j < 8; j++){ float d = y[j]-mu; var += d*d; }
    var += __shfl_xor(var, 1); var += __shfl_xor(var, 2); var += __shfl_xor(var, 4);
    var *= (1.f/64.f);
    float rstd = rsqrtf(var + LNEPS);
    us8 ho, hto;
    #pragma unroll
    for (int j = 0; j < 8; j++){
        float o = (y[j]-mu)*rstd*ln_g[sub*8+j] + ln_b[sub*8+j];
        o = o > 0.f ? o : 0.f;
        ho[j]  = __half_as_ushort(__float2half(o));
        hto[j] = __half_as_ushort(__float2half(dv*o));
    }
    ((us8*)h_dst)[(size_t)v*8 + sub]  = ho;
    ((us8*)ht_dst)[(size_t)v*8 + sub] = hto;
}

// ---------- gather + fuse + LN + readout (layer 2) — writes only out[] ----------
__global__ __launch_bounds__(256) void k_gfuse_ro(
        const __half* __restrict__ ht_src, const __half* __restrict__ h_src,
        const __half* __restrict__ G16,
        const float* __restrict__ a_s, const float* __restrict__ a_d,
        const float* __restrict__ mxs, const float* __restrict__ dinv,
        const int* __restrict__ row_ptr, const int* __restrict__ re_col,
        const int* __restrict__ col_ptr, const int* __restrict__ ce_row,
        const _Float16* __restrict__ Wt16, const float* __restrict__ b2c,
        const float* __restrict__ ln_g, const float* __restrict__ ln_b,
        const _Float16* __restrict__ Wr16, const float* __restrict__ rb1,
        const float* __restrict__ rW2, const float* __restrict__ rb2,
        float* __restrict__ out, int N){
    __shared__ _Float16 Wl[8192];        // 16 KB fused weights
    __shared__ _Float16 Wr[2048];        // 4 KB readout W1 [k][j]
    __shared__ _Float16 inb[4][8][128];
    {
        const half8* src = (const half8*)Wt16;
        half8* dst = (half8*)Wl;
        for (int i = threadIdx.x; i < 1024; i += 256) dst[i] = src[i];
        const half8* src2 = (const half8*)Wr16;
        half8* dst2 = (half8*)Wr;
        for (int i = threadIdx.x; i < 256; i += 256) dst2[i] = src2[i];
    }
    __syncthreads();
    int lane = threadIdx.x & 63;
    int wv = threadIdx.x >> 6;
    int grp = lane >> 3, sub = lane & 7, hh = sub >> 1;
    int wid = (blockIdx.x*blockDim.x + threadIdx.x) >> 6;
    int v = wid*8 + grp;
    if (v >= N) return;
    const us8* htb = (const us8*)ht_src;
    const us8* gb  = (const us8*)G16;
    const unsigned* mup = (const unsigned*)mxs;
    float sh = leaky(decf(mup[hh]) + decf(mup[4+hh]));
    int rs = row_ptr[v], re = row_ptr[v+1];
    float a0[8] = {0,0,0,0,0,0,0,0}, a1[8] = {0,0,0,0,0,0,0,0};
    float a2[8] = {0,0,0,0,0,0,0,0}, a3[8] = {0,0,0,0,0,0,0,0};
    int i = rs;
    for (; i + 3 < re; i += 4){
        us8 q0 = htb[(size_t)re_col[i]*8 + sub];
        us8 q1 = htb[(size_t)re_col[i+1]*8 + sub];
        us8 q2 = htb[(size_t)re_col[i+2]*8 + sub];
        us8 q3 = htb[(size_t)re_col[i+3]*8 + sub];
        #pragma unroll
        for (int j = 0; j < 8; j++){
            a0[j] += __half2float(__ushort_as_half(q0[j]));
            a1[j] += __half2float(__ushort_as_half(q1[j]));
            a2[j] += __half2float(__ushort_as_half(q2[j]));
            a3[j] += __half2float(__ushort_as_half(q3[j]));
        }
    }
    for (; i < re; i++){
        us8 q0 = htb[(size_t)re_col[i]*8 + sub];
        #pragma unroll
        for (int j = 0; j < 8; j++) a0[j] += __half2float(__ushort_as_half(q0[j]));
    }
    float dv = dinv[v];
    float ajv[8];
    #pragma unroll
    for (int j = 0; j < 8; j++) ajv[j] = dv*((a0[j]+a1[j]) + (a2[j]+a3[j]));
    float adv = a_d[v*4+hh];
    float eesl = __expf(leaky(a_s[v*4+hh] + adv) - sh);
    float s0 = eesl, s1 = 0.f, s2 = 0.f, s3 = 0.f;
    {
        us8 g0 = gb[(size_t)v*8 + sub];
        #pragma unroll
        for (int j = 0; j < 8; j++){
            a0[j] = eesl * __half2float(__ushort_as_half(g0[j]));
            a1[j] = 0.f; a2[j] = 0.f; a3[j] = 0.f;
        }
    }
    int cs = col_ptr[v], ce = col_ptr[v+1];
    i = cs;
    for (; i + 3 < ce; i += 4){
        int r0 = ce_row[i], r1 = ce_row[i+1], r2 = ce_row[i+2], r3 = ce_row[i+3];
        float e0 = __expf(leaky(a_s[r0*4+hh] + adv) - sh);
        float e1 = __expf(leaky(a_s[r1*4+hh] + adv) - sh);
        float e2 = __expf(leaky(a_s[r2*4+hh] + adv) - sh);
        float e3 = __expf(leaky(a_s[r3*4+hh] + adv) - sh);
        us8 q0 = gb[(size_t)r0*8 + sub];
        us8 q1 = gb[(size_t)r1*8 + sub];
        us8 q2 = gb[(size_t)r2*8 + sub];
        us8 q3 = gb[(size_t)r3*8 + sub];
        #pragma unroll
        for (int j = 0; j < 8; j++){
            a0[j] += e0 * __half2float(__ushort_as_half(q0[j]));
            a1[j] += e1 * __half2float(__ushort_as_half(q1[j]));
            a2[j] += e2 * __half2float(__ushort_as_half(q2[j]));
            a3[j] += e3 * __half2float(__ushort_as_half(q3[j]));
        }
        s0 += e0; s1 += e1; s2 += e2; s3 += e3;
    }
    for (; i < ce; i++){
        int r0 = ce_row[i];
        float e0 = __expf(leaky(a_s[r0*4+hh] + adv) - sh);
        us8 q0 = gb[(size_t)r0*8 + sub];
        #pragma unroll
        for (int j = 0; j < 8; j++) a0[j] += e0 * __half2float(__ushort_as_half(q0[j]));
        s0 += e0;
    }
    float inv = 1.f/((s0+s1)+(s2+s3));
    _Float16* myin = inb[wv][grp];
    half8 ha, hx;
    #pragma unroll
    for (int j = 0; j < 8; j++){
        ha[j] = (_Float16)ajv[j];
        hx[j] = (_Float16)(((a0[j]+a1[j]) + (a2[j]+a3[j]))*inv);
    }
    *(half8*)(myin + sub*8)      = ha;
    *(half8*)(myin + 64 + sub*8) = hx;
    float y[8];
    us8 hr = ((const us8*)h_src)[(size_t)v*8 + sub];
    #pragma unroll
    for (int j = 0; j < 8; j++)
        y[j] = b2c[sub*8+j] + __half2float(__ushort_as_half(hr[j]));
    for (int pp = 0; pp < 16; pp++){
        half8 ib = *(half8*)(myin + pp*8);
        #pragma unroll
        for (int e = 0; e < 8; e++){
            float xin = (float)ib[e];
            half8 w = *(half8*)(Wl + (pp*8+e)*64 + sub*8);
            #pragma unroll
            for (int j = 0; j < 8; j++) y[j] += xin * (float)w[j];
        }
    }
    float s = ((y[0]+y[1])+(y[2]+y[3])) + ((y[4]+y[5])+(y[6]+y[7]));
    s += __shfl_xor(s, 1); s += __shfl_xor(s, 2); s += __shfl_xor(s, 4);
    float mu = s * (1.f/64.f);
    float var = 0.f;
    #pragma unroll
    for (int j = 0; j < 8; j++){ float d = y[j]-mu; var += d*d; }
    var += __shfl_xor(var, 1); var += __shfl_xor(var, 2); var += __shfl_xor(var, 4);
    var *= (1.f/64.f);
    float rstd = rsqrtf(var + LNEPS);
    half8 hov;
    #pragma unroll
    for (int j = 0; j < 8; j++){
        float o = (y[j]-mu)*rstd*ln_g[sub*8+j] + ln_b[sub*8+j];
        o = o > 0.f ? o : 0.f;
        hov[j] = (_Float16)o;
    }
    *(half8*)(myin + sub*8) = hov;
    float h1[4];
    #pragma unroll
    for (int m = 0; m < 4; m++) h1[m] = rb1[sub*4+m];
    for (int pp = 0; pp < 8; pp++){
        half8 ib = *(half8*)(myin + pp*8);
        #pragma unroll
        for (int e = 0; e < 8; e++){
            float xin = (float)ib[e];
            half4v wr = *(half4v*)(Wr + (pp*8+e)*32 + sub*4);
            #pragma unroll
            for (int m = 0; m < 4; m++) h1[m] += xin * (float)wr[m];
        }
    }
    float p = 0.f;
    #pragma unroll
    for (int m = 0; m < 4; m++){
        float t = h1[m] > 0.f ? h1[m] : 0.f;
        p += t * rW2[sub*4+m];
    }
    p += __shfl_xor(p, 1); p += __shfl_xor(p, 2); p += __shfl_xor(p, 4);
    if (sub == 0)
        out[v] = 1.f/(1.f + __expf(-(p + rb2[0])));
}

extern "C" void kernel_launch(void* const* d_in, const int* in_sizes, int n_in,
                              void* d_out, int out_size, void* d_ws, size_t ws_size,
                              hipStream_t stream){
    const ushort_t* xs = (const ushort_t*)d_in[0];
    const int*      ei = (const int*)d_in[1];

    int N = in_sizes[0] / 64;
    int E = in_sizes[1] / 2;
    const int* row = ei;
    const int* col = ei + E;
    int NBK = (N + BWD - 1) / BWD;

    size_t mirF = (size_t)N*32;

    float* f = (float*)d_ws;
    size_t o = 0;
    int*   flags = (int*)(f + o); o += 16;
    float* P     = f + o; o += P_TOTAL + 63;
    __half* h16a  = (__half*)(f + o); o += mirF;
    __half* ht16a = (__half*)(f + o); o += mirF;
    __half* h16b  = (__half*)(f + o); size_t boff = o; o += mirF;
    __half* ht16b = (__half*)(f + o); size_t coff = o; o += mirF;
    unsigned* stage_r = (unsigned*)(f + boff);   // alias: stage dead before h16b written
    unsigned* stage_c = (unsigned*)(f + coff);
    __half* G16  = (__half*)(f + o); o += mirF;
    float* a_s   = f + o; o += (size_t)N*4;
    float* a_d   = f + o; o += (size_t)N*4;
    float* mxs   = f + o; o += 32;          // 3 layer slots x 8 + pad
    float* dinv  = f + o; o += ((size_t)N + 15) & ~15ull;
    int* bcnt    = (int*)(f + o); o += 512;
    int* bptr_r  = (int*)(f + o); o += 512;
    int* bptr_c  = (int*)(f + o); o += 512;
    int* bcur_r  = (int*)(f + o); o += 512;
    int* bcur_c  = (int*)(f + o); o += 512;
    int* ptr_r   = (int*)(f + o); o += ((size_t)N + 16) & ~15ull;
    int* ptr_c   = (int*)(f + o); o += ((size_t)N + 16) & ~15ull;
    int* re_col  = (int*)(f + o); o += (size_t)E;
    int* ce_row  = (int*)(f + o); o += (size_t)E;
    float* b2c   = f + o; o += 3*64;
    _Float16* Wt16 = (_Float16*)(f + o); o += 3*4096;   // 3*8192 fp16 fused weights
    _Float16* Bg   = (_Float16*)(f + o); o += 3*2560;   // 3*5120 fp16 G-frags
    _Float16* Wr16 = (_Float16*)(f + o); o += 1024;     // 2048 fp16 readout W1

    const float* emb_W   = P + 0;
    const float* emb_b   = P + 4096;
    const float* e8_W    = P + 4160;
    const float* gat_W   = P + 16448;
    const float* att_src = P + 28736;
    const float* att_dst = P + 28928;
    const float* gat_b   = P + 29120;
    const float* fus_W   = P + 29312;
    const float* fus_b   = P + 53888;
    const float* ln_g    = P + 54080;
    const float* ln_b    = P + 54272;
    const float* r_W1    = P + 54464;
    const float* r_b1    = P + 56512;
    const float* r_W2    = P + 56544;
    const float* r_b2    = P + 56576;

    hipMemsetAsync(bcnt, 0, 512*sizeof(int), stream);
    k_init<<<CONV_BLKS + 256, 256, 0, stream>>>(
        d_in[2],d_in[3],d_in[4],d_in[5],d_in[6],d_in[7],d_in[8],d_in[9],
        d_in[10],d_in[11],d_in[12],d_in[13],d_in[14],d_in[15],d_in[16],
        d_in[0], row, col, E, NBK, flags, P, bcnt, (unsigned*)mxs);

    int prwblk = (PRW_B3 + 255) / 256;
    kb_scanprew<<<2 + prwblk, 256, 0, stream>>>(bcnt, bptr_r, bptr_c, bcur_r, bcur_c,
                                                NBK, E, fus_W, e8_W, gat_b, fus_b,
                                                gat_W, att_src, att_dst, r_W1,
                                                Wt16, b2c, Bg, Wr16);
    kb_bin<<<512, 1024, 0, stream>>>(row, col, bcur_r, bcur_c, stage_r, stage_c, NBK, E);
    kb_place<<<2*NBK, 1024, 0, stream>>>(stage_r, stage_c, bptr_r, bptr_c,
                                         ptr_r, ptr_c, re_col, ce_row, dinv, NBK, N, E);

    int tiles = (N + 15) / 16;
    int fgrid = (tiles + 7) / 8;
    int ggrid = (N + 31) / 32;
    k_embed_g<<<fgrid, 256, 0, stream>>>(xs, flags, emb_W, emb_b, dinv, Bg,
                                         h16a, ht16a, G16, a_s, a_d, mxs, N);
    // L0: (a,·)->b
    k_gfuse<<<ggrid, 256, 0, stream>>>(ht16a, h16a, G16, a_s, a_d, mxs, dinv,
                                       ptr_r, re_col, ptr_c, ce_row,
                                       Wt16, b2c, ln_g, ln_b, h16b, ht16b, N);
    k_gat_g<<<fgrid, 256, 0, stream>>>(h16b, Bg + 5120, G16, a_s, a_d, mxs + 8, N);
    // L1: b->a
    k_gfuse<<<ggrid, 256, 0, stream>>>(ht16b, h16b, G16, a_s, a_d, mxs + 8, dinv,
                                       ptr_r, re_col, ptr_c, ce_row,
                                       Wt16 + 8192, b2c + 64, ln_g + 64, ln_b + 64,
                                       h16a, ht16a, N);
    k_gat_g<<<fgrid, 256, 0, stream>>>(h16a, Bg + 2*5120, G16, a_s, a_d, mxs + 16, N);
    // L2: a -> readout
    k_gfuse_ro<<<ggrid, 256, 0, stream>>>(ht16a, h16a, G16, a_s, a_d, mxs + 16, dinv,
                                          ptr_r, re_col, ptr_c, ce_row,
                                          Wt16 + 2*8192, b2c + 128, ln_g + 128, ln_b + 128,
                                          Wr16, r_b1, r_W2, r_b2, (float*)d_out, N);
}

// Round 12
// 635.310 us; speedup vs baseline: 1.0543x; 1.0543x over previous
//
#include <hip/hip_runtime.h>
#include <hip/hip_bf16.h>
#include <hip/hip_fp16.h>

typedef __hip_bfloat16 bf16;
typedef unsigned short ushort_t;
typedef unsigned short us8 __attribute__((ext_vector_type(8)));
typedef _Float16 half8 __attribute__((ext_vector_type(8)));
typedef float f32x4 __attribute__((ext_vector_type(4)));

#define NEG 0.2f
#define LNEPS 1e-5f
#define BWD 512                 // CSR bucket width (nodes)

__device__ __forceinline__ int plaus(unsigned int lo){
    lo &= 0x7FFFu;
    if (lo == 0) return 1;
    unsigned int ex = (lo >> 7) & 0xFF;
    return (ex >= 100 && ex <= 140) ? 1 : 0;
}

__device__ __forceinline__ float decode_slot(const ushort_t* s, long long i, int fl){
    long long base = i << fl;
    unsigned int hi = s[base + fl];
    unsigned int lo = s[base];
    unsigned int bits = (hi << 16) | (lo * (unsigned int)fl);
    return __uint_as_float(bits);
}

// order-preserving float<->uint encoding for atomicMax on floats (incl. negatives)
__device__ __forceinline__ unsigned encf(float f){
    int b = __float_as_int(f);
    return (b >= 0) ? ((unsigned)b | 0x80000000u) : (unsigned)(~b);
}
__device__ __forceinline__ float decf(unsigned k){
    return (k & 0x80000000u) ? __uint_as_float(k & 0x7FFFFFFFu)
                             : __uint_as_float(~k);
}

// ---------- init: param convert (inline detect) + flags + mxs + edge histogram ----------
#define P_TOTAL 56577
#define CONV_BLKS 222
__global__ __launch_bounds__(256) void k_init(const void* p0, const void* p1, const void* p2,
        const void* p3, const void* p4, const void* p5, const void* p6, const void* p7,
        const void* p8, const void* p9, const void* p10, const void* p11, const void* p12,
        const void* p13, const void* p14, const void* xs,
        const int* __restrict__ row, const int* __restrict__ col, int E, int NBK,
        int* flags, float* P, int* bcnt, unsigned* mxsu){
    __shared__ int lh[512];
    int t = threadIdx.x;
    if (blockIdx.x >= CONV_BLKS){
        int hb = blockIdx.x - CONV_BLKS;
        for (int i = t; i < 2*NBK; i += 256) lh[i] = 0;
        __syncthreads();
        for (long long e = (long long)hb*256 + t; e < E; e += (long long)256*256){
            atomicAdd(&lh[row[e] >> 9], 1);
            atomicAdd(&lh[NBK + (col[e] >> 9)], 1);
        }
        __syncthreads();
        for (int i = t; i < 2*NBK; i += 256){
            int v = lh[i];
            if (v) atomicAdd(&bcnt[i], v);
        }
        return;
    }
    if (blockIdx.x == 0){
        if (t < 9){
            const void* dt[9] = {xs, p0, p2, p3, p4, p5, p7, p11, p13};
            const ushort_t* w = (const ushort_t*)dt[t];
            int all_bf = 1;
            for (int i = 0; i < 16; i++) all_bf &= plaus((unsigned int)w[i]);
            flags[t] = all_bf ? 0 : 1;
        } else if (t == 9){
            const ushort_t* w = (const ushort_t*)p9;
            flags[9] = (w[0] == 0x3F80u) ? 0 : 1;
        }
        if (t < 32) mxsu[t] = 0u;            // encoded -inf for 3 layer slots
    }
    int idx = blockIdx.x*256 + t;
    if (idx >= P_TOTAL) return;
    const int sizes[15] = {4096,64,12288,12288,192,192,192,24576,192,192,192,2048,32,32,1};
    const int fidx[15]  = {1,  -1,  2,    3,    4,  5,  -1, 6,    -1, 9,  -1, 7,   -1,8, -1};
    const void* ptrs[15] = {p0,p1,p2,p3,p4,p5,p6,p7,p8,p9,p10,p11,p12,p13,p14};
    int s = 0, base = 0;
    while (idx - base >= sizes[s]){ base += sizes[s]; s++; }
    int li = idx - base;
    int fi = fidx[s];
    int fl = 0;
    if (fi == 9){
        const ushort_t* w = (const ushort_t*)ptrs[s];
        fl = (w[0] == 0x3F80u) ? 0 : 1;
    } else if (fi >= 0){
        const ushort_t* w = (const ushort_t*)ptrs[s];
        int all_bf = 1;
        for (int i = 0; i < 16; i++) all_bf &= plaus((unsigned int)w[i]);
        fl = all_bf ? 0 : 1;
    }
    P[idx] = decode_slot((const ushort_t*)ptrs[s], li, fl);
}

// ---------- scan + weight precompute, one launch (block-role split) ----------
#define PRW_B0 (3*8192)
#define PRW_B1 (PRW_B0 + 192)
#define PRW_B2 (PRW_B1 + 3*5120)
__global__ __launch_bounds__(256) void kb_scanprew(const int* __restrict__ bcnt,
        int* __restrict__ bptr_r, int* __restrict__ bptr_c,
        int* __restrict__ bcur_r, int* __restrict__ bcur_c, int NBK, int E,
        const float* __restrict__ fus_W, const float* __restrict__ e8_W,
        const float* __restrict__ gat_b, const float* __restrict__ fus_b,
        const float* __restrict__ gat_W, const float* __restrict__ att_src,
        const float* __restrict__ att_dst,
        _Float16* __restrict__ Bfrag, float* __restrict__ b2c, _Float16* __restrict__ Bg){
    __shared__ int sh[256];
    int t = threadIdx.x;
    if (blockIdx.x < 2){
        int side = blockIdx.x;
        const int* c = bcnt + side*NBK;
        int* bp = side ? bptr_c : bptr_r;
        int* bc = side ? bcur_c : bcur_r;
        int v = (t < NBK) ? c[t] : 0;
        sh[t] = v; __syncthreads();
        for (int off = 1; off < 256; off <<= 1){
            int add = (t >= off) ? sh[t-off] : 0;
            __syncthreads();
            sh[t] += add;
            __syncthreads();
        }
        if (t < NBK){ int e = sh[t] - v; bp[t] = e; bc[t] = e; }
        if (t == 0) bp[NBK] = E;
        return;
    }
    int idx = (blockIdx.x - 2)*256 + t;
    if (idx < PRW_B0){
        int i = idx / 8192; int rem = idx & 8191;
        int j = rem & 7, lane = (rem >> 3) & 63, kk = (rem >> 9) & 3, tt = rem >> 11;
        int k = kk*32 + (lane >> 4)*8 + j;
        int n = tt*16 + (lane & 15);
        float v;
        if (k < 64){
            const float* fw = fus_W + (size_t)i*8192 + (size_t)n*128;
            const float* ew = e8_W + (size_t)i*4096;
            float acc = 0.f;
            for (int p = 0; p < 64; p++) acc += fw[p] * ew[p*64 + k];
            v = acc;
        } else {
            v = fus_W[(size_t)i*8192 + (size_t)n*128 + k];
        }
        Bfrag[idx] = (_Float16)v;
    } else if (idx < PRW_B1){
        int t2 = idx - PRW_B0;
        int i = t2 >> 6, j = t2 & 63;
        const float* fw = fus_W + (size_t)i*8192 + (size_t)j*128 + 64;
        float acc = fus_b[i*64+j];
        for (int p = 0; p < 64; p++) acc += gat_b[i*64+p] * fw[p];
        b2c[t2] = acc;
    } else if (idx < PRW_B2){
        int t3 = idx - PRW_B1;
        int i = t3 / 5120; int rem = t3 % 5120;
        int j = rem & 7, lane = (rem >> 3) & 63, kk = (rem >> 9) & 1, tt = rem >> 10;
        int k = kk*32 + (lane >> 4)*8 + j;
        int nn = lane & 15;
        float v;
        if (tt < 4){
            v = gat_W[(size_t)i*4096 + k*64 + (tt*16 + nn)];
        } else if (nn < 8){
            int hx = nn >> 1;
            const float* att = (nn & 1) ? att_dst : att_src;
            float acc = 0.f;
            for (int cc = 0; cc < 16; cc++)
                acc += gat_W[(size_t)i*4096 + k*64 + hx*16 + cc] * att[i*64 + hx*16 + cc];
            v = acc;
        } else {
            v = 0.f;
        }
        Bg[t3] = (_Float16)v;
    }
}

// both sides in one launch; stage packed to 4B: (in-bucket node)<<23 | payload
__global__ __launch_bounds__(1024) void kb_bin(const int* __restrict__ row,
        const int* __restrict__ col, int* __restrict__ bcur_r, int* __restrict__ bcur_c,
        unsigned* __restrict__ stage_r, unsigned* __restrict__ stage_c, int NBK, int E){
    __shared__ int lh[256], lbase[256];
    int side = blockIdx.x >> 8;
    int bid  = blockIdx.x & 255;
    const int* key = side ? col : row;
    const int* pay = side ? row : col;
    int* bcur = side ? bcur_c : bcur_r;
    unsigned* stage = side ? stage_c : stage_r;
    int t = threadIdx.x;
    for (long long tile = (long long)bid*1024; tile < E; tile += (long long)256*1024){
        for (int i = t; i < NBK; i += 1024) lh[i] = 0;
        __syncthreads();
        int e = (int)tile + t;
        int k = 0, p = 0, b = -1, rank = 0;
        if (e < E){
            k = key[e]; p = pay[e]; b = k >> 9;
            rank = atomicAdd(&lh[b], 1);
        }
        __syncthreads();
        for (int i = t; i < NBK; i += 1024){
            int c = lh[i];
            lbase[i] = c ? atomicAdd(&bcur[i], c) : 0;
        }
        __syncthreads();
        if (b >= 0) stage[lbase[b] + rank] = ((unsigned)(k & 511) << 23) | (unsigned)p;
        __syncthreads();
    }
}

// both sides in one launch: blocks 0..NBK-1 row, NBK..2NBK-1 col
__global__ __launch_bounds__(1024) void kb_place(const unsigned* __restrict__ stage_r,
        const unsigned* __restrict__ stage_c, const int* __restrict__ bptr_r,
        const int* __restrict__ bptr_c, int* __restrict__ ptr_r, int* __restrict__ ptr_c,
        int* __restrict__ re_col, int* __restrict__ ce_row,
        float* __restrict__ dinv, int NBK, int N, int E){
    __shared__ int lcnt[BWD], lsc[BWD], lcur[BWD];
    int side = blockIdx.x >= NBK;
    int b = blockIdx.x - (side ? NBK : 0);
    const unsigned* stage = side ? stage_c : stage_r;
    const int* bptr = side ? bptr_c : bptr_r;
    int* ptr = side ? ptr_c : ptr_r;
    int* outarr = side ? ce_row : re_col;
    int wantdinv = side;
    int s = bptr[b], e = bptr[b+1];
    int t = threadIdx.x;
    if (t < BWD) lcnt[t] = 0;
    __syncthreads();
    for (int i = s + t; i < e; i += 1024)
        atomicAdd(&lcnt[stage[i] >> 23], 1);
    __syncthreads();
    if (t < BWD) lsc[t] = lcnt[t];
    __syncthreads();
    for (int off = 1; off < BWD; off <<= 1){
        int add = (t >= off && t < BWD) ? lsc[t-off] : 0;
        __syncthreads();
        if (t < BWD) lsc[t] += add;
        __syncthreads();
    }
    if (t < BWD){
        int node = (b << 9) + t;
        int excl = lsc[t] - lcnt[t];
        lcur[t] = excl;
        if (node < N){
            ptr[node] = s + excl;
            if (wantdinv) dinv[node] = lcnt[t] > 0 ? rsqrtf((float)lcnt[t]) : 0.f;
        }
    }
    if (b == 0 && t == 0) ptr[N] = E;
    __syncthreads();
    for (int i = s + t; i < e; i += 1024){
        unsigned rec = stage[i];
        int pos = s + atomicAdd(&lcur[rec >> 23], 1);
        outarr[pos] = (int)(rec & 0x7FFFFFu);
    }
}

// ---------- embed + layer-0 G projection (vectorized x loads, tbuf transpose) ----------
__global__ __launch_bounds__(256) void k_embed_g(const ushort_t* __restrict__ xs,
        const int* __restrict__ flags, const float* __restrict__ W,
        const float* __restrict__ b, const float* __restrict__ dinv,
        const _Float16* __restrict__ Bgn,
        __half* __restrict__ h16, __half* __restrict__ ht16, __half* __restrict__ G16,
        float* __restrict__ a_s, float* __restrict__ a_d, float* __restrict__ mxs, int N){
    __shared__ float redm[4][8];
    __shared__ _Float16 tbuf[4][1024];
    int lane = threadIdx.x & 63;
    int wv = threadIdx.x >> 6;
    int q = lane >> 4, c = lane & 15;
    _Float16* tb = tbuf[wv];
    int fl = flags[0];
    half8 Be[4][2];
    #pragma unroll
    for (int t = 0; t < 4; t++){
        #pragma unroll
        for (int kk = 0; kk < 2; kk++){
            half8 v;
            #pragma unroll
            for (int j = 0; j < 8; j++)
                v[j] = (_Float16)W[(t*16 + c)*64 + kk*32 + q*8 + j];
            Be[t][kk] = v;
        }
    }
    half8 Bg[5][2];
    const half8* Bgp = (const half8*)Bgn;
    #pragma unroll
    for (int t = 0; t < 5; t++)
        #pragma unroll
        for (int kk = 0; kk < 2; kk++)
            Bg[t][kk] = Bgp[(t*2+kk)*64 + lane];
    float bj[4];
    #pragma unroll
    for (int t = 0; t < 4; t++) bj[t] = b[t*16 + c];
    float lmax = -1e30f;
    int tiles = (N + 15) >> 4;
    int wid = (blockIdx.x*blockDim.x + threadIdx.x) >> 6;
    int nw  = (gridDim.x*blockDim.x) >> 6;
    for (int tile = wid; tile < tiles; tile += nw){
        int nb = tile << 4;
        int anode = nb + c; if (anode >= N) anode = N - 1;
        half8 A0, A1;
        if (fl == 0){
            const us8* xv = (const us8*)xs;
            us8 r0 = xv[(size_t)anode*8 + q];
            us8 r1 = xv[(size_t)anode*8 + 4 + q];
            #pragma unroll
            for (int j = 0; j < 8; j++){
                A0[j] = (_Float16)__uint_as_float((unsigned)r0[j] << 16);
                A1[j] = (_Float16)__uint_as_float((unsigned)r1[j] << 16);
            }
        } else {
            const f32x4* xf = (const f32x4*)xs;
            f32x4 f0 = xf[(size_t)anode*16 + q*2];
            f32x4 f1 = xf[(size_t)anode*16 + q*2 + 1];
            f32x4 f2 = xf[(size_t)anode*16 + 8 + q*2];
            f32x4 f3 = xf[(size_t)anode*16 + 8 + q*2 + 1];
            #pragma unroll
            for (int j = 0; j < 4; j++){
                A0[j] = (_Float16)f0[j]; A0[4+j] = (_Float16)f1[j];
                A1[j] = (_Float16)f2[j]; A1[4+j] = (_Float16)f3[j];
            }
        }
        f32x4 acc[4];
        #pragma unroll
        for (int t = 0; t < 4; t++){
            f32x4 z = {0.f, 0.f, 0.f, 0.f};
            z = __builtin_amdgcn_mfma_f32_16x16x32_f16(A0, Be[t][0], z, 0, 0, 0);
            z = __builtin_amdgcn_mfma_f32_16x16x32_f16(A1, Be[t][1], z, 0, 0, 0);
            acc[t] = z;
        }
        #pragma unroll
        for (int r = 0; r < 4; r++){
            int node = nb + q*4 + r;
            int nd2 = q*4 + r;
            #pragma unroll
            for (int t = 0; t < 4; t++){
                float out = acc[t][r] + bj[t];
                int byte = nd2*128 + (t*16 + c)*2;
                byte ^= (nd2 & 7) << 4;
                *(_Float16*)((char*)tb + byte) = (_Float16)out;
                if (node < N){
                    h16[(size_t)node*64 + t*16 + c] = __float2half(out);
                    ht16[(size_t)node*64 + t*16 + c] = __float2half(dinv[node]*out);
                }
            }
        }
        int b0 = (c*128 + 16*q) ^ ((c & 7) << 4);
        int b1 = (c*128 + 64 + 16*q) ^ ((c & 7) << 4);
        half8 A0g = *(half8*)((char*)tb + b0);
        half8 A1g = *(half8*)((char*)tb + b1);
        f32x4 gacc[5];
        #pragma unroll
        for (int t = 0; t < 5; t++){
            f32x4 z = {0.f, 0.f, 0.f, 0.f};
            z = __builtin_amdgcn_mfma_f32_16x16x32_f16(A0g, Bg[t][0], z, 0, 0, 0);
            z = __builtin_amdgcn_mfma_f32_16x16x32_f16(A1g, Bg[t][1], z, 0, 0, 0);
            gacc[t] = z;
        }
        #pragma unroll
        for (int r = 0; r < 4; r++) lmax = fmaxf(lmax, gacc[4][r]);
        #pragma unroll
        for (int r = 0; r < 4; r++){
            int node = nb + q*4 + r;
            if (node < N){
                #pragma unroll
                for (int t = 0; t < 4; t++)
                    G16[(size_t)node*64 + t*16 + c] = __float2half(gacc[t][r]);
                if (c < 8){
                    int hx = c >> 1;
                    if (c & 1) a_d[node*4+hx] = gacc[4][r];
                    else       a_s[node*4+hx] = gacc[4][r];
                }
            }
        }
    }
    lmax = fmaxf(lmax, __shfl_xor(lmax, 16));
    lmax = fmaxf(lmax, __shfl_xor(lmax, 32));
    if (lane < 8) redm[wv][lane] = lmax;
    __syncthreads();
    if (threadIdx.x < 8){
        float m = fmaxf(fmaxf(redm[0][threadIdx.x], redm[1][threadIdx.x]),
                        fmaxf(redm[2][threadIdx.x], redm[3][threadIdx.x]));
        int hx = threadIdx.x >> 1;
        int ix = (threadIdx.x & 1) ? 4 + hx : hx;
        atomicMax((unsigned*)mxs + ix, encf(m));
    }
}

__device__ __forceinline__ float leaky(float t){ return t > 0.f ? t : NEG*t; }

// ---------- gather: 8 nodes/wave, 8 lanes/node, 16B loads (proven form) ----------
__global__ __launch_bounds__(256) void k_gather(const __half* __restrict__ ht16,
        const __half* __restrict__ G16,
        const float* __restrict__ a_s, const float* __restrict__ a_d,
        const float* __restrict__ mxs, const float* __restrict__ dinv,
        const int* __restrict__ row_ptr, const int* __restrict__ re_col,
        const int* __restrict__ col_ptr, const int* __restrict__ ce_row,
        __half* __restrict__ Aj16, __half* __restrict__ xg16, int N){
    int lane = threadIdx.x & 63;
    int grp  = lane >> 3;
    int sub  = lane & 7;
    int hh   = sub >> 1;
    int wid  = (blockIdx.x*blockDim.x + threadIdx.x) >> 6;
    int v    = wid*8 + grp;
    if (v >= N) return;
    const us8* htb = (const us8*)ht16;
    const us8* gb  = (const us8*)G16;
    const unsigned* mu = (const unsigned*)mxs;
    float sh = leaky(decf(mu[hh]) + decf(mu[4+hh]));
    int rs = row_ptr[v], re = row_ptr[v+1];
    float a0[8] = {0,0,0,0,0,0,0,0}, a1[8] = {0,0,0,0,0,0,0,0};
    float a2[8] = {0,0,0,0,0,0,0,0}, a3[8] = {0,0,0,0,0,0,0,0};
    int i = rs;
    for (; i + 3 < re; i += 4){
        us8 q0 = htb[(size_t)re_col[i]*8 + sub];
        us8 q1 = htb[(size_t)re_col[i+1]*8 + sub];
        us8 q2 = htb[(size_t)re_col[i+2]*8 + sub];
        us8 q3 = htb[(size_t)re_col[i+3]*8 + sub];
        #pragma unroll
        for (int j = 0; j < 8; j++){
            a0[j] += __half2float(__ushort_as_half(q0[j]));
            a1[j] += __half2float(__ushort_as_half(q1[j]));
            a2[j] += __half2float(__ushort_as_half(q2[j]));
            a3[j] += __half2float(__ushort_as_half(q3[j]));
        }
    }
    for (; i < re; i++){
        us8 q0 = htb[(size_t)re_col[i]*8 + sub];
        #pragma unroll
        for (int j = 0; j < 8; j++) a0[j] += __half2float(__ushort_as_half(q0[j]));
    }
    float dv = dinv[v];
    us8 pa;
    #pragma unroll
    for (int j = 0; j < 8; j++)
        pa[j] = __half_as_ushort(__float2half(dv*((a0[j]+a1[j]) + (a2[j]+a3[j]))));
    ((us8*)Aj16)[(size_t)v*8 + sub] = pa;
    float adv = a_d[v*4+hh];
    float eesl = __expf(leaky(a_s[v*4+hh] + adv) - sh);
    float s0 = eesl, s1 = 0.f, s2 = 0.f, s3 = 0.f;
    {
        us8 g0 = gb[(size_t)v*8 + sub];
        #pragma unroll
        for (int j = 0; j < 8; j++){
            a0[j] = eesl * __half2float(__ushort_as_half(g0[j]));
            a1[j] = 0.f; a2[j] = 0.f; a3[j] = 0.f;
        }
    }
    int cs = col_ptr[v], ce = col_ptr[v+1];
    i = cs;
    for (; i + 3 < ce; i += 4){
        int r0 = ce_row[i], r1 = ce_row[i+1], r2 = ce_row[i+2], r3 = ce_row[i+3];
        float e0 = __expf(leaky(a_s[r0*4+hh] + adv) - sh);
        float e1 = __expf(leaky(a_s[r1*4+hh] + adv) - sh);
        float e2 = __expf(leaky(a_s[r2*4+hh] + adv) - sh);
        float e3 = __expf(leaky(a_s[r3*4+hh] + adv) - sh);
        us8 q0 = gb[(size_t)r0*8 + sub];
        us8 q1 = gb[(size_t)r1*8 + sub];
        us8 q2 = gb[(size_t)r2*8 + sub];
        us8 q3 = gb[(size_t)r3*8 + sub];
        #pragma unroll
        for (int j = 0; j < 8; j++){
            a0[j] += e0 * __half2float(__ushort_as_half(q0[j]));
            a1[j] += e1 * __half2float(__ushort_as_half(q1[j]));
            a2[j] += e2 * __half2float(__ushort_as_half(q2[j]));
            a3[j] += e3 * __half2float(__ushort_as_half(q3[j]));
        }
        s0 += e0; s1 += e1; s2 += e2; s3 += e3;
    }
    for (; i < ce; i++){
        int r0 = ce_row[i];
        float e0 = __expf(leaky(a_s[r0*4+hh] + adv) - sh);
        us8 q0 = gb[(size_t)r0*8 + sub];
        #pragma unroll
        for (int j = 0; j < 8; j++) a0[j] += e0 * __half2float(__ushort_as_half(q0[j]));
        s0 += e0;
    }
    float inv = 1.f/((s0+s1)+(s2+s3));
    us8 px;
    #pragma unroll
    for (int j = 0; j < 8; j++)
        px[j] = __half_as_ushort(__float2half(((a0[j]+a1[j]) + (a2[j]+a3[j]))*inv));
    ((us8*)xg16)[(size_t)v*8 + sub] = px;
}

// ---------- fuse+G (layers 0,1): fusion epilogue + NEXT layer's G via LDS transpose ----------
__global__ __launch_bounds__(256) void k_fuse_g(
        const __half* __restrict__ Aj16, const __half* __restrict__ xg16,
        const float* __restrict__ dinv, __half* __restrict__ h16,
        __half* __restrict__ ht16,
        const _Float16* __restrict__ Bfrag, const float* __restrict__ b2c,
        const float* __restrict__ ln_g, const float* __restrict__ ln_b,
        const _Float16* __restrict__ Bgn, __half* __restrict__ G16,
        float* __restrict__ a_s, float* __restrict__ a_d,
        float* __restrict__ mxs_next, int N){
    __shared__ float redm[4][8];
    __shared__ _Float16 tbuf[4][1024];
    int lane = threadIdx.x & 63;
    int wv = threadIdx.x >> 6;
    int q = lane >> 4, c = lane & 15;
    _Float16* tb = tbuf[wv];
    half8 B[4][4];
    const half8* Bp = (const half8*)Bfrag;
    #pragma unroll
    for (int t = 0; t < 4; t++)
        #pragma unroll
        for (int kk = 0; kk < 4; kk++)
            B[t][kk] = Bp[(t*4+kk)*64 + lane];
    half8 Bg[5][2];
    const half8* Bgp = (const half8*)Bgn;
    #pragma unroll
    for (int t = 0; t < 5; t++)
        #pragma unroll
        for (int kk = 0; kk < 2; kk++)
            Bg[t][kk] = Bgp[(t*2+kk)*64 + lane];
    float bj[4], lg[4], lb[4];
    #pragma unroll
    for (int t = 0; t < 4; t++){
        int n = t*16 + c;
        bj[t] = b2c[n]; lg[t] = ln_g[n]; lb[t] = ln_b[n];
    }
    float lmax = -1e30f;
    int tiles = (N + 15) >> 4;
    int wid = (blockIdx.x*blockDim.x + threadIdx.x) >> 6;
    int nw  = (gridDim.x*blockDim.x) >> 6;
    for (int tile = wid; tile < tiles; tile += nw){
        int nb = tile << 4;
        int anode = nb + c; if (anode >= N) anode = N - 1;
        const half8* ap = (const half8*)(Aj16 + (size_t)anode*64);
        const half8* xp = (const half8*)(xg16 + (size_t)anode*64);
        half8 A0 = ap[q];
        half8 A1 = ap[4 + q];
        half8 A2 = xp[q];
        half8 A3 = xp[4 + q];
        f32x4 acc[4];
        #pragma unroll
        for (int t = 0; t < 4; t++){
            f32x4 z = {0.f, 0.f, 0.f, 0.f};
            z = __builtin_amdgcn_mfma_f32_16x16x32_f16(A0, B[t][0], z, 0, 0, 0);
            z = __builtin_amdgcn_mfma_f32_16x16x32_f16(A1, B[t][1], z, 0, 0, 0);
            z = __builtin_amdgcn_mfma_f32_16x16x32_f16(A2, B[t][2], z, 0, 0, 0);
            z = __builtin_amdgcn_mfma_f32_16x16x32_f16(A3, B[t][3], z, 0, 0, 0);
            acc[t] = z;
        }
        float y[4][4];     // [t][r]
        #pragma unroll
        for (int r = 0; r < 4; r++){
            int node = nb + q*4 + r;
            int nd = node < N ? node : N - 1;
            #pragma unroll
            for (int t = 0; t < 4; t++)
                y[t][r] = acc[t][r] + bj[t]
                        + __half2float(h16[(size_t)nd*64 + t*16 + c]);
        }
        #pragma unroll
        for (int r = 0; r < 4; r++){
            int node = nb + q*4 + r;
            float s = (y[0][r] + y[1][r]) + (y[2][r] + y[3][r]);
            #pragma unroll
            for (int o = 1; o < 16; o <<= 1) s += __shfl_xor(s, o);
            float mu = s * (1.f/64.f);
            float d0 = y[0][r]-mu, d1 = y[1][r]-mu, d2 = y[2][r]-mu, d3 = y[3][r]-mu;
            float var = (d0*d0 + d1*d1) + (d2*d2 + d3*d3);
            #pragma unroll
            for (int o = 1; o < 16; o <<= 1) var += __shfl_xor(var, o);
            var *= (1.f/64.f);
            float rstd = rsqrtf(var + LNEPS);
            int nd2 = q*4 + r;
            #pragma unroll
            for (int t = 0; t < 4; t++){
                float out = (y[t][r]-mu)*rstd*lg[t] + lb[t];
                out = out > 0.f ? out : 0.f;
                int byte = nd2*128 + (t*16 + c)*2;
                byte ^= (nd2 & 7) << 4;
                *(_Float16*)((char*)tb + byte) = (_Float16)out;
                if (node < N){
                    h16[(size_t)node*64 + t*16 + c] = __float2half(out);
                    ht16[(size_t)node*64 + t*16 + c] = __float2half(dinv[node]*out);
                }
            }
        }
        int b0 = (c*128 + 16*q) ^ ((c & 7) << 4);
        int b1 = (c*128 + 64 + 16*q) ^ ((c & 7) << 4);
        half8 A0g = *(half8*)((char*)tb + b0);
        half8 A1g = *(half8*)((char*)tb + b1);
        f32x4 gacc[5];
        #pragma unroll
        for (int t = 0; t < 5; t++){
            f32x4 z = {0.f, 0.f, 0.f, 0.f};
            z = __builtin_amdgcn_mfma_f32_16x16x32_f16(A0g, Bg[t][0], z, 0, 0, 0);
            z = __builtin_amdgcn_mfma_f32_16x16x32_f16(A1g, Bg[t][1], z, 0, 0, 0);
            gacc[t] = z;
        }
        #pragma unroll
        for (int r = 0; r < 4; r++) lmax = fmaxf(lmax, gacc[4][r]);
        #pragma unroll
        for (int r = 0; r < 4; r++){
            int node = nb + q*4 + r;
            if (node < N){
                #pragma unroll
                for (int t = 0; t < 4; t++)
                    G16[(size_t)node*64 + t*16 + c] = __float2half(gacc[t][r]);
                if (c < 8){
                    int hx = c >> 1;
                    if (c & 1) a_d[node*4+hx] = gacc[4][r];
                    else       a_s[node*4+hx] = gacc[4][r];
                }
            }
        }
    }
    lmax = fmaxf(lmax, __shfl_xor(lmax, 16));
    lmax = fmaxf(lmax, __shfl_xor(lmax, 32));
    if (lane < 8) redm[wv][lane] = lmax;
    __syncthreads();
    if (threadIdx.x < 8){
        float m = fmaxf(fmaxf(redm[0][threadIdx.x], redm[1][threadIdx.x]),
                        fmaxf(redm[2][threadIdx.x], redm[3][threadIdx.x]));
        int hx = threadIdx.x >> 1;
        int ix = (threadIdx.x & 1) ? 4 + hx : hx;
        atomicMax((unsigned*)mxs_next + ix, encf(m));
    }
}

// ---------- fuse layer 2 + readout (tbuf transpose -> r_W1 MFMA -> w2 dot -> sigmoid) ----
__global__ __launch_bounds__(256) void k_fuse_ro(
        const __half* __restrict__ Aj16, const __half* __restrict__ xg16,
        const __half* __restrict__ h16,
        const _Float16* __restrict__ Bfrag, const float* __restrict__ b2c,
        const float* __restrict__ ln_g, const float* __restrict__ ln_b,
        const float* __restrict__ rW1, const float* __restrict__ rb1,
        const float* __restrict__ rW2, const float* __restrict__ rb2,
        float* __restrict__ out, int N){
    __shared__ _Float16 tbuf[4][1024];
    int lane = threadIdx.x & 63;
    int wv = threadIdx.x >> 6;
    int q = lane >> 4, c = lane & 15;
    _Float16* tb = tbuf[wv];
    half8 B[4][4];
    const half8* Bp = (const half8*)Bfrag;
    #pragma unroll
    for (int t = 0; t < 4; t++)
        #pragma unroll
        for (int kk = 0; kk < 4; kk++)
            B[t][kk] = Bp[(t*4+kk)*64 + lane];
    half8 B1r[2][2];
    #pragma unroll
    for (int t = 0; t < 2; t++){
        #pragma unroll
        for (int kk = 0; kk < 2; kk++){
            half8 v;
            #pragma unroll
            for (int j = 0; j < 8; j++)
                v[j] = (_Float16)rW1[(t*16 + c)*64 + kk*32 + q*8 + j];
            B1r[t][kk] = v;
        }
    }
    float bj[4], lg[4], lb[4];
    #pragma unroll
    for (int t = 0; t < 4; t++){
        int n = t*16 + c;
        bj[t] = b2c[n]; lg[t] = ln_g[n]; lb[t] = ln_b[n];
    }
    float b1v[2] = {rb1[c], rb1[16 + c]};
    float w2a = rW2[c], w2b = rW2[16 + c];
    float b2v = rb2[0];
    int tiles = (N + 15) >> 4;
    int wid = (blockIdx.x*blockDim.x + threadIdx.x) >> 6;
    int nw  = (gridDim.x*blockDim.x) >> 6;
    for (int tile = wid; tile < tiles; tile += nw){
        int nb = tile << 4;
        int anode = nb + c; if (anode >= N) anode = N - 1;
        const half8* ap = (const half8*)(Aj16 + (size_t)anode*64);
        const half8* xp = (const half8*)(xg16 + (size_t)anode*64);
        half8 A0 = ap[q];
        half8 A1 = ap[4 + q];
        half8 A2 = xp[q];
        half8 A3 = xp[4 + q];
        f32x4 acc[4];
        #pragma unroll
        for (int t = 0; t < 4; t++){
            f32x4 z = {0.f, 0.f, 0.f, 0.f};
            z = __builtin_amdgcn_mfma_f32_16x16x32_f16(A0, B[t][0], z, 0, 0, 0);
            z = __builtin_amdgcn_mfma_f32_16x16x32_f16(A1, B[t][1], z, 0, 0, 0);
            z = __builtin_amdgcn_mfma_f32_16x16x32_f16(A2, B[t][2], z, 0, 0, 0);
            z = __builtin_amdgcn_mfma_f32_16x16x32_f16(A3, B[t][3], z, 0, 0, 0);
            acc[t] = z;
        }
        float y[4][4];     // [t][r]
        #pragma unroll
        for (int r = 0; r < 4; r++){
            int node = nb + q*4 + r;
            int nd = node < N ? node : N - 1;
            #pragma unroll
            for (int t = 0; t < 4; t++)
                y[t][r] = acc[t][r] + bj[t]
                        + __half2float(h16[(size_t)nd*64 + t*16 + c]);
        }
        #pragma unroll
        for (int r = 0; r < 4; r++){
            float s = (y[0][r] + y[1][r]) + (y[2][r] + y[3][r]);
            #pragma unroll
            for (int o = 1; o < 16; o <<= 1) s += __shfl_xor(s, o);
            float mu = s * (1.f/64.f);
            float d0 = y[0][r]-mu, d1 = y[1][r]-mu, d2 = y[2][r]-mu, d3 = y[3][r]-mu;
            float var = (d0*d0 + d1*d1) + (d2*d2 + d3*d3);
            #pragma unroll
            for (int o = 1; o < 16; o <<= 1) var += __shfl_xor(var, o);
            var *= (1.f/64.f);
            float rstd = rsqrtf(var + LNEPS);
            int nd2 = q*4 + r;
            #pragma unroll
            for (int t = 0; t < 4; t++){
                float outv = (y[t][r]-mu)*rstd*lg[t] + lb[t];
                outv = outv > 0.f ? outv : 0.f;
                int byte = nd2*128 + (t*16 + c)*2;
                byte ^= (nd2 & 7) << 4;
                *(_Float16*)((char*)tb + byte) = (_Float16)outv;
            }
        }
        int b0 = (c*128 + 16*q) ^ ((c & 7) << 4);
        int b1 = (c*128 + 64 + 16*q) ^ ((c & 7) << 4);
        half8 A0g = *(half8*)((char*)tb + b0);
        half8 A1g = *(half8*)((char*)tb + b1);
        f32x4 racc[2];
        #pragma unroll
        for (int t = 0; t < 2; t++){
            f32x4 z = {0.f, 0.f, 0.f, 0.f};
            z = __builtin_amdgcn_mfma_f32_16x16x32_f16(A0g, B1r[t][0], z, 0, 0, 0);
            z = __builtin_amdgcn_mfma_f32_16x16x32_f16(A1g, B1r[t][1], z, 0, 0, 0);
            racc[t] = z;
        }
        #pragma unroll
        for (int r = 0; r < 4; r++){
            int node = nb + q*4 + r;
            float h1a = racc[0][r] + b1v[0]; h1a = h1a > 0.f ? h1a : 0.f;
            float h1b = racc[1][r] + b1v[1]; h1b = h1b > 0.f ? h1b : 0.f;
            float p = h1a*w2a + h1b*w2b;
            p += __shfl_xor(p, 1);
            p += __shfl_xor(p, 2);
            p += __shfl_xor(p, 4);
            p += __shfl_xor(p, 8);
            if (c == 0 && node < N){
                float z = p + b2v;
                out[node] = 1.f/(1.f + __expf(-z));
            }
        }
    }
}

extern "C" void kernel_launch(void* const* d_in, const int* in_sizes, int n_in,
                              void* d_out, int out_size, void* d_ws, size_t ws_size,
                              hipStream_t stream){
    const ushort_t* xs = (const ushort_t*)d_in[0];
    const int*      ei = (const int*)d_in[1];

    int N = in_sizes[0] / 64;
    int E = in_sizes[1] / 2;
    const int* row = ei;
    const int* col = ei + E;
    int NBK = (N + BWD - 1) / BWD;

    size_t mirF = (size_t)N*32;
    size_t stageF = (size_t)E;                       // packed 4B records
    size_t aliasF = stageF > mirF ? stageF : mirF;

    float* f = (float*)d_ws;
    size_t o = 0;
    int*   flags = (int*)(f + o); o += 16;
    float* P     = f + o; o += P_TOTAL + 63;
    __half* h16  = (__half*)(f + o); o += mirF;
    __half* ht16 = (__half*)(f + o); o += mirF;
    __half* G16  = (__half*)(f + o); o += mirF;
    __half* Aj16 = (__half*)(f + o); size_t aoff = o; o += aliasF;
    __half* xg16 = (__half*)(f + o); size_t xoff = o; o += aliasF;
    unsigned* stage_r = (unsigned*)(f + aoff);       // alias: dead before Aj16 written
    unsigned* stage_c = (unsigned*)(f + xoff);
    float* a_s   = f + o; o += (size_t)N*4;
    float* a_d   = f + o; o += (size_t)N*4;
    float* mxs   = f + o; o += 32;          // 3 layer slots x 8 + pad
    float* dinv  = f + o; o += ((size_t)N + 15) & ~15ull;
    int* bcnt    = (int*)(f + o); o += 512;
    int* bptr_r  = (int*)(f + o); o += 512;
    int* bptr_c  = (int*)(f + o); o += 512;
    int* bcur_r  = (int*)(f + o); o += 512;
    int* bcur_c  = (int*)(f + o); o += 512;
    int* ptr_r   = (int*)(f + o); o += ((size_t)N + 16) & ~15ull;
    int* ptr_c   = (int*)(f + o); o += ((size_t)N + 16) & ~15ull;
    int* re_col  = (int*)(f + o); o += (size_t)E;
    int* ce_row  = (int*)(f + o); o += (size_t)E;
    float* b2c   = f + o; o += 3*64;
    _Float16* Bfrag = (_Float16*)(f + o); o += 3*4096;   // 3*8192 fp16
    _Float16* Bg    = (_Float16*)(f + o); o += 3*2560;   // 3*5120 fp16 (5 t-tiles)

    const float* emb_W   = P + 0;
    const float* emb_b   = P + 4096;
    const float* e8_W    = P + 4160;
    const float* gat_W   = P + 16448;
    const float* att_src = P + 28736;
    const float* att_dst = P + 28928;
    const float* gat_b   = P + 29120;
    const float* fus_W   = P + 29312;
    const float* fus_b   = P + 53888;
    const float* ln_g    = P + 54080;
    const float* ln_b    = P + 54272;
    const float* r_W1    = P + 54464;
    const float* r_b1    = P + 56512;
    const float* r_W2    = P + 56544;
    const float* r_b2    = P + 56576;

    hipMemsetAsync(bcnt, 0, 512*sizeof(int), stream);
    k_init<<<CONV_BLKS + 256, 256, 0, stream>>>(
        d_in[2],d_in[3],d_in[4],d_in[5],d_in[6],d_in[7],d_in[8],d_in[9],
        d_in[10],d_in[11],d_in[12],d_in[13],d_in[14],d_in[15],d_in[16],
        d_in[0], row, col, E, NBK, flags, P, bcnt, (unsigned*)mxs);

    int prwblk = (PRW_B2 + 255) / 256;
    kb_scanprew<<<2 + prwblk, 256, 0, stream>>>(bcnt, bptr_r, bptr_c, bcur_r, bcur_c,
                                                NBK, E, fus_W, e8_W, gat_b, fus_b,
                                                gat_W, att_src, att_dst, Bfrag, b2c, Bg);
    kb_bin<<<512, 1024, 0, stream>>>(row, col, bcur_r, bcur_c, stage_r, stage_c, NBK, E);
    kb_place<<<2*NBK, 1024, 0, stream>>>(stage_r, stage_c, bptr_r, bptr_c,
                                         ptr_r, ptr_c, re_col, ce_row, dinv, NBK, N, E);

    int tiles = (N + 15) / 16;
    int fgrid = (tiles + 7) / 8;
    int ggrid = (N + 31) / 32;
    k_embed_g<<<fgrid, 256, 0, stream>>>(xs, flags, emb_W, emb_b, dinv, Bg,
                                         h16, ht16, G16, a_s, a_d, mxs, N);
    for (int i = 0; i < 3; i++){
        k_gather<<<ggrid, 256, 0, stream>>>(ht16, G16, a_s, a_d, mxs + i*8, dinv,
                                            ptr_r, re_col, ptr_c, ce_row,
                                            Aj16, xg16, N);
        if (i < 2){
            k_fuse_g<<<fgrid, 256, 0, stream>>>(Aj16, xg16, dinv, h16, ht16,
                                                Bfrag + (size_t)i*8192, b2c + i*64,
                                                ln_g + i*64, ln_b + i*64,
                                                Bg + (size_t)(i+1)*5120, G16,
                                                a_s, a_d, mxs + (i+1)*8, N);
        } else {
            k_fuse_ro<<<fgrid, 256, 0, stream>>>(Aj16, xg16, h16,
                                                 Bfrag + (size_t)i*8192, b2c + i*64,
                                                 ln_g + i*64, ln_b + i*64,
                                                 r_W1, r_b1, r_W2, r_b2,
                                                 (float*)d_out, N);
        }
    }
}